// Round 14
// baseline (1509.822 us; speedup 1.0000x reference)
//
#include <hip/hip_runtime.h>
#include <hip/hip_bf16.h>

#define D 128

__device__ __forceinline__ float bf2f(unsigned short u) {
  return __uint_as_float(((unsigned int)u) << 16);
}

// flags: [0..4]=float tensor is-bf16 (emb,W1,b1,W2,b2), [5]=ints-int64,
//        [6]=max(x), [7]=max(batch), [8]=x/batch swapped

// length-aware per-tensor dtype detect: sample even ushorts under the
// bf16 hypothesis (index 2k, k<K, K=min(256, n/2)); bf16 data lands in
// exponent window [100,140] (any sane scale) or is 0; f32 data's even
// ushorts are mantissa noise (~16% in window).
__global__ void k_detect_f(const unsigned short* __restrict__ u16,
                           int n, int* __restrict__ flagSlot) {
  __shared__ int cnt;
  int K = n / 2 < 256 ? n / 2 : 256;
  if (threadIdx.x == 0) cnt = 0;
  __syncthreads();
  if (threadIdx.x < K) {
    unsigned short u = u16[threadIdx.x * 2];
    int e = (u >> 7) & 0xFF;
    if (u == 0 || (e >= 100 && e <= 140)) atomicAdd(&cnt, 1);
  }
  __syncthreads();
  if (threadIdx.x == 0) *flagSlot = (cnt * 2 >= K) ? 1 : 0;
}

__global__ void k_detect_i(const unsigned int* __restrict__ ei32,
                           int* __restrict__ flagSlot) {
  __shared__ int z;
  if (threadIdx.x == 0) z = 0;
  __syncthreads();
  if (ei32[threadIdx.x * 2 + 1] == 0u) atomicAdd(&z, 1);
  __syncthreads();
  if (threadIdx.x == 0) *flagSlot = (z >= 60) ? 1 : 0;
}

__global__ void k_conv(const void* __restrict__ src, float* __restrict__ dst,
                       int n, const int* __restrict__ flagSlot) {
  int i = blockIdx.x * blockDim.x + threadIdx.x;
  if (i >= n) return;
  if (*flagSlot) dst[i] = bf2f(((const unsigned short*)src)[i]);
  else           dst[i] = ((const float*)src)[i];
}

__global__ void k_convi(const void* __restrict__ src, int* __restrict__ dst,
                        long long ofs, int n, int hi, const int* __restrict__ flag64) {
  int i = blockIdx.x * blockDim.x + threadIdx.x;
  if (i >= n) return;
  int v = (*flag64) ? (int)((const long long*)src)[ofs + i]
                    : ((const int*)src)[ofs + i];
  v = v < 0 ? 0 : v;
  v = v > hi - 1 ? hi - 1 : v;
  dst[i] = v;
}

__global__ void k_max(const int* __restrict__ a, int n, int* __restrict__ out) {
  int i = blockIdx.x * blockDim.x + threadIdx.x;
  if (i < n) atomicMax(out, a[i]);
}

__global__ void k_sdecide(int* __restrict__ flag) {
  if (threadIdx.x == 0 && blockIdx.x == 0) flag[8] = (flag[6] < flag[7]) ? 1 : 0;
}

__global__ void k_fixswap(int* __restrict__ xs, int* __restrict__ bs, int nn,
                          int vocab, int ng, const int* __restrict__ flag) {
  int i = blockIdx.x * blockDim.x + threadIdx.x;
  if (i >= nn) return;
  int a = xs[i], b = bs[i];
  if (flag[8]) { int t = a; a = b; b = t; }
  a = a < 0 ? 0 : (a > vocab - 1 ? vocab - 1 : a);
  b = b < 0 ? 0 : (b > ng - 1 ? ng - 1 : b);
  xs[i] = a;
  bs[i] = b;
}

__global__ void k_count(const int* __restrict__ dstA, int* __restrict__ indeg,
                        int ne) {
  int e = blockIdx.x * blockDim.x + threadIdx.x;
  if (e < ne) atomicAdd(&indeg[dstA[e]], 1);
}

__global__ void k_dis(const int* __restrict__ indeg, float* __restrict__ dis,
                      int nn) {
  int i = blockIdx.x * blockDim.x + threadIdx.x;
  if (i < nn) dis[i] = rsqrtf((float)indeg[i] + 1.0f);  // +1 self-loop
}

__global__ void k_cnt(const int* __restrict__ batch, int* __restrict__ cnt,
                      int nn) {
  int i = blockIdx.x * blockDim.x + threadIdx.x;
  if (i < nn) atomicAdd(&cnt[batch[i]], 1);
}

// ---------------- G = emb @ W1 (shown-JAX orientation: W[k*128+c]) --------
__global__ void k_gemm_dumb(const float* __restrict__ A,
                            const float* __restrict__ W,
                            float* __restrict__ OUT, int rows) {
  int idx = blockIdx.x * blockDim.x + threadIdx.x;
  if (idx >= rows * D) return;
  int r = idx >> 7, c = idx & 127;
  const float* a = A + (size_t)r * D;
  float acc = 0.f;
  for (int k = 0; k < D; ++k) acc += a[k] * W[k * D + c];
  OUT[idx] = acc;
}

// ---------------- layer-1 scatter: AGG1[dst] += norm * G[x[src]] ----------
__global__ __launch_bounds__(256) void k_edge1(const int* __restrict__ srcA,
                                               const int* __restrict__ dstA,
                                               const int* __restrict__ x,
                                               const float* __restrict__ dis,
                                               const float* __restrict__ G,
                                               float* __restrict__ AGG1,
                                               int ne, int nn) {
  int w0 = (blockIdx.x * blockDim.x + threadIdx.x) >> 6;
  if (w0 >= ne + nn) return;
  int lane = threadIdx.x & 63;
  int s, d;
  float wgt;
  if (w0 < ne) {
    s = srcA[w0]; d = dstA[w0]; wgt = dis[s] * dis[d];
  } else {
    s = d = w0 - ne; float t = dis[s]; wgt = t * t;
  }
  float2 gv = ((const float2*)(G + (size_t)x[s] * D))[lane];
  atomicAdd(&AGG1[(size_t)d * D + lane * 2],     wgt * gv.x);
  atomicAdd(&AGG1[(size_t)d * D + lane * 2 + 1], wgt * gv.y);
}

__global__ void k_relu(float* __restrict__ AGG1, const float* __restrict__ b1,
                       int total) {
  int i = blockIdx.x * blockDim.x + threadIdx.x;
  if (i >= total) return;
  AGG1[i] = fmaxf(AGG1[i] + b1[i & 127], 0.f);
}

// ---------------- layer-2 scatter fused with pool: P[batch[dst]] += w*H1[src]
__global__ __launch_bounds__(256) void k_edge2(const int* __restrict__ srcA,
                                               const int* __restrict__ dstA,
                                               const int* __restrict__ batch,
                                               const float* __restrict__ dis,
                                               const float* __restrict__ H1,
                                               float* __restrict__ P,
                                               int ne, int nn) {
  int w0 = (blockIdx.x * blockDim.x + threadIdx.x) >> 6;
  if (w0 >= ne + nn) return;
  int lane = threadIdx.x & 63;
  int s, d;
  float wgt;
  if (w0 < ne) {
    s = srcA[w0]; d = dstA[w0]; wgt = dis[s] * dis[d];
  } else {
    s = d = w0 - ne; float t = dis[s]; wgt = t * t;
  }
  float2 hv = ((const float2*)(H1 + (size_t)s * D))[lane];
  int g = batch[d];
  atomicAdd(&P[(size_t)g * D + lane * 2],     wgt * hv.x);
  atomicAdd(&P[(size_t)g * D + lane * 2 + 1], wgt * hv.y);
}

// ---------------- out[g][c] = (P[g]/cnt[g]) @ W2 + b2, FLOAT32 out --------
__global__ void k_out_dumb(const float* __restrict__ P,
                           const int* __restrict__ cnt,
                           const float* __restrict__ W2,
                           const float* __restrict__ b2,
                           float* __restrict__ Out, int ng) {
  int idx = blockIdx.x * blockDim.x + threadIdx.x;
  if (idx >= ng * D) return;
  int g = idx >> 7, c = idx & 127;
  int m = cnt[g];
  float inv = (m > 0) ? (1.0f / (float)m) : 0.0f;
  const float* pr = P + (size_t)g * D;
  float acc = 0.f;
  for (int k = 0; k < D; ++k) acc += pr[k] * W2[k * D + c];
  acc *= inv;
  if (m > 0) acc += b2[c];
  Out[idx] = acc;   // float32 output
}

extern "C" void kernel_launch(void* const* d_in, const int* in_sizes, int n_in,
                              void* d_out, int out_size, void* d_ws, size_t ws_size,
                              hipStream_t stream) {
  const void* xr = d_in[0];
  const void* eir = d_in[1];
  const void* batchr = d_in[2];
  const void* emb = d_in[3];
  const void* W1 = d_in[4];
  const void* b1 = d_in[5];
  const void* W2 = d_in[6];
  const void* b2 = d_in[7];
  float* out = (float*)d_out;

  const int nn = in_sizes[0];
  const int ne = in_sizes[1] / 2;
  const int vocab = in_sizes[3] / D;
  const int ng = out_size / D;

  char* p = (char*)d_ws;
  auto alloc = [&](size_t bytes) -> char* {
    char* r = p;
    p += (bytes + 511) & ~(size_t)511;
    return r;
  };
  int* flag = (int*)alloc(512);
  int* xs = (int*)alloc((size_t)nn * 4);
  int* srcs = (int*)alloc((size_t)ne * 4);
  int* dsts = (int*)alloc((size_t)ne * 4);
  int* batchs = (int*)alloc((size_t)nn * 4);
  int* indeg = (int*)alloc((size_t)nn * 4);
  float* dis = (float*)alloc((size_t)nn * 4);
  int* cnt = (int*)alloc((size_t)ng * 4);
  float* embf = (float*)alloc((size_t)vocab * D * 4);
  float* W1f = (float*)alloc((size_t)D * D * 4);
  float* b1f = (float*)alloc((size_t)D * 4);
  float* W2f = (float*)alloc((size_t)D * D * 4);
  float* b2f = (float*)alloc((size_t)D * 4);
  float* G = (float*)alloc((size_t)vocab * D * 4);
  float* AGG1 = (float*)alloc((size_t)nn * D * 4);
  float* P = (float*)alloc((size_t)ng * D * 4);

  hipMemsetAsync(flag, 0, 512, stream);

  // per-tensor float dtype detection
  k_detect_f<<<1, 256, 0, stream>>>((const unsigned short*)emb, vocab * D, flag + 0);
  k_detect_f<<<1, 256, 0, stream>>>((const unsigned short*)W1, D * D, flag + 1);
  k_detect_f<<<1, 256, 0, stream>>>((const unsigned short*)b1, D, flag + 2);
  k_detect_f<<<1, 256, 0, stream>>>((const unsigned short*)W2, D * D, flag + 3);
  k_detect_f<<<1, 256, 0, stream>>>((const unsigned short*)b2, D, flag + 4);
  k_detect_i<<<1, 64, 0, stream>>>((const unsigned int*)eir, flag + 5);

  k_conv<<<(vocab * D + 255) / 256, 256, 0, stream>>>(emb, embf, vocab * D, flag + 0);
  k_conv<<<(D * D + 255) / 256, 256, 0, stream>>>(W1, W1f, D * D, flag + 1);
  k_conv<<<1, 128, 0, stream>>>(b1, b1f, D, flag + 2);
  k_conv<<<(D * D + 255) / 256, 256, 0, stream>>>(W2, W2f, D * D, flag + 3);
  k_conv<<<1, 128, 0, stream>>>(b2, b2f, D, flag + 4);

  // planar (2,E) layout, as-shown direction
  k_convi<<<(nn + 255) / 256, 256, 0, stream>>>(xr, xs, 0, nn, 0x7fffffff, flag + 5);
  k_convi<<<(ne + 255) / 256, 256, 0, stream>>>(eir, srcs, 0, ne, nn, flag + 5);
  k_convi<<<(ne + 255) / 256, 256, 0, stream>>>(eir, dsts, ne, ne, nn, flag + 5);
  k_convi<<<(nn + 255) / 256, 256, 0, stream>>>(batchr, batchs, 0, nn, 0x7fffffff, flag + 5);

  k_max<<<(nn + 255) / 256, 256, 0, stream>>>(xs, nn, flag + 6);
  k_max<<<(nn + 255) / 256, 256, 0, stream>>>(batchs, nn, flag + 7);
  k_sdecide<<<1, 64, 0, stream>>>(flag);
  k_fixswap<<<(nn + 255) / 256, 256, 0, stream>>>(xs, batchs, nn, vocab, ng, flag);

  hipMemsetAsync(indeg, 0, (size_t)nn * 4, stream);
  hipMemsetAsync(cnt, 0, (size_t)ng * 4, stream);
  hipMemsetAsync(AGG1, 0, (size_t)nn * D * 4, stream);
  hipMemsetAsync(P, 0, (size_t)ng * D * 4, stream);

  k_count<<<(ne + 255) / 256, 256, 0, stream>>>(dsts, indeg, ne);
  k_dis<<<(nn + 255) / 256, 256, 0, stream>>>(indeg, dis, nn);
  k_cnt<<<(nn + 255) / 256, 256, 0, stream>>>(batchs, cnt, nn);

  // G = emb @ W1, hoisted through the embedding gather
  k_gemm_dumb<<<(vocab * D + 255) / 256, 256, 0, stream>>>(embf, W1f, G, vocab);

  {
    long long thr = ((long long)ne + nn) * 64;
    k_edge1<<<(int)((thr + 255) / 256), 256, 0, stream>>>(srcs, dsts, xs, dis, G,
                                                          AGG1, ne, nn);
  }
  k_relu<<<(int)(((size_t)nn * D + 255) / 256), 256, 0, stream>>>(AGG1, b1f, nn * D);
  {
    long long thr = ((long long)ne + nn) * 64;
    k_edge2<<<(int)((thr + 255) / 256), 256, 0, stream>>>(srcs, dsts, batchs, dis,
                                                          AGG1, P, ne, nn);
  }
  // out = (P/cnt) @ W2 + b2, float32
  k_out_dumb<<<(ng * D + 255) / 256, 256, 0, stream>>>(P, cnt, W2f, b2f, out, ng);
}

// Round 15
// 601.359 us; speedup vs baseline: 2.5107x; 2.5107x over previous
//
#include <hip/hip_runtime.h>
#include <hip/hip_bf16.h>

#define D 128

__device__ __forceinline__ float bf2f(unsigned short u) {
  return __uint_as_float(((unsigned int)u) << 16);
}
__device__ __forceinline__ unsigned short f2bf(float f) {
  unsigned int x = __float_as_uint(f);
  x += 0x7fff + ((x >> 16) & 1);
  return (unsigned short)(x >> 16);
}

// flags: [0..4]=float tensor is-bf16 (emb,W1,b1,W2,b2), [5]=ints-int64,
//        [6]=max(x), [7]=max(batch), [8]=x/batch swapped

__global__ void k_detect_f(const unsigned short* __restrict__ u16,
                           int n, int* __restrict__ flagSlot) {
  __shared__ int cnt;
  int K = n / 2 < 256 ? n / 2 : 256;
  if (threadIdx.x == 0) cnt = 0;
  __syncthreads();
  if (threadIdx.x < K) {
    unsigned short u = u16[threadIdx.x * 2];
    int e = (u >> 7) & 0xFF;
    if (u == 0 || (e >= 100 && e <= 140)) atomicAdd(&cnt, 1);
  }
  __syncthreads();
  if (threadIdx.x == 0) *flagSlot = (cnt * 2 >= K) ? 1 : 0;
}

__global__ void k_detect_i(const unsigned int* __restrict__ ei32,
                           int* __restrict__ flagSlot) {
  __shared__ int z;
  if (threadIdx.x == 0) z = 0;
  __syncthreads();
  if (ei32[threadIdx.x * 2 + 1] == 0u) atomicAdd(&z, 1);
  __syncthreads();
  if (threadIdx.x == 0) *flagSlot = (z >= 60) ? 1 : 0;
}

__global__ void k_conv(const void* __restrict__ src, float* __restrict__ dst,
                       int n, const int* __restrict__ flagSlot) {
  int i = blockIdx.x * blockDim.x + threadIdx.x;
  if (i >= n) return;
  if (*flagSlot) dst[i] = bf2f(((const unsigned short*)src)[i]);
  else           dst[i] = ((const float*)src)[i];
}

__global__ void k_convi(const void* __restrict__ src, int* __restrict__ dst,
                        long long ofs, int n, int hi, const int* __restrict__ flag64) {
  int i = blockIdx.x * blockDim.x + threadIdx.x;
  if (i >= n) return;
  int v = (*flag64) ? (int)((const long long*)src)[ofs + i]
                    : ((const int*)src)[ofs + i];
  v = v < 0 ? 0 : v;
  v = v > hi - 1 ? hi - 1 : v;
  dst[i] = v;
}

__global__ void k_max(const int* __restrict__ a, int n, int* __restrict__ out) {
  int i = blockIdx.x * blockDim.x + threadIdx.x;
  if (i < n) atomicMax(out, a[i]);
}

__global__ void k_sdecide(int* __restrict__ flag) {
  if (threadIdx.x == 0 && blockIdx.x == 0) flag[8] = (flag[6] < flag[7]) ? 1 : 0;
}

__global__ void k_fixswap(int* __restrict__ xs, int* __restrict__ bs, int nn,
                          int vocab, int ng, const int* __restrict__ flag) {
  int i = blockIdx.x * blockDim.x + threadIdx.x;
  if (i >= nn) return;
  int a = xs[i], b = bs[i];
  if (flag[8]) { int t = a; a = b; b = t; }
  a = a < 0 ? 0 : (a > vocab - 1 ? vocab - 1 : a);
  b = b < 0 ? 0 : (b > ng - 1 ? ng - 1 : b);
  xs[i] = a;
  bs[i] = b;
}

// ---------------- CSR build (atomics only on small int arrays) ------------
__global__ void k_count(const int* __restrict__ dstA, int* __restrict__ indeg,
                        int ne) {
  int e = blockIdx.x * blockDim.x + threadIdx.x;
  if (e < ne) atomicAdd(&indeg[dstA[e]], 1);
}

__global__ __launch_bounds__(256) void k_bsum(const int* __restrict__ indeg,
                                              int* __restrict__ bsum, int nn) {
  __shared__ int red[256];
  int b = blockIdx.x, t = threadIdx.x;
  int s = 0;
  #pragma unroll
  for (int j = 0; j < 4; ++j) {
    int idx = b * 1024 + t + j * 256;
    if (idx < nn) s += indeg[idx];
  }
  red[t] = s;
  __syncthreads();
  for (int w = 128; w > 0; w >>= 1) {
    if (t < w) red[t] += red[t + w];
    __syncthreads();
  }
  if (t == 0) bsum[b] = red[0];
}

__global__ void k_scan2(int* __restrict__ bsum, int nb) {
  if (blockIdx.x == 0 && threadIdx.x == 0) {
    int run = 0;
    for (int i = 0; i < nb; ++i) { int s = bsum[i]; bsum[i] = run; run += s; }
  }
}

__global__ void k_off(const int* __restrict__ indeg, const int* __restrict__ bsum,
                      int* __restrict__ off, int* __restrict__ cursor, int nn) {
  if (threadIdx.x != 0) return;
  int b = blockIdx.x;
  int run = bsum[b];
  for (int i = 0; i < 1024; ++i) {
    int idx = b * 1024 + i;
    if (idx < nn) {
      off[idx] = run;
      cursor[idx] = run;
      run += indeg[idx];
    }
  }
}

__global__ void k_dis(const int* __restrict__ indeg, float* __restrict__ dis,
                      int nn) {
  int i = blockIdx.x * blockDim.x + threadIdx.x;
  if (i < nn) dis[i] = rsqrtf((float)indeg[i] + 1.0f);  // +1 self-loop
}

__global__ void k_cnt(const int* __restrict__ batch, int* __restrict__ cnt,
                      int nn) {
  int i = blockIdx.x * blockDim.x + threadIdx.x;
  if (i < nn) atomicAdd(&cnt[batch[i]], 1);
}

__global__ void k_fill(const int* __restrict__ srcA, const int* __restrict__ dstA,
                       const float* __restrict__ dis, int* __restrict__ cursor,
                       int* __restrict__ csr_src, float* __restrict__ csr_norm,
                       int ne) {
  int e = blockIdx.x * blockDim.x + threadIdx.x;
  if (e >= ne) return;
  int d = dstA[e], s = srcA[e];
  int pp = atomicAdd(&cursor[d], 1);
  csr_src[pp] = s;
  csr_norm[pp] = dis[s] * dis[d];
}

// ---------------- G = emb @ W1 --------------------------------------------
__global__ void k_gemm_dumb(const float* __restrict__ A,
                            const float* __restrict__ W,
                            float* __restrict__ OUT, int rows) {
  int idx = blockIdx.x * blockDim.x + threadIdx.x;
  if (idx >= rows * D) return;
  int r = idx >> 7, c = idx & 127;
  const float* a = A + (size_t)r * D;
  float acc = 0.f;
  for (int k = 0; k < D; ++k) acc += a[k] * W[k * D + c];
  OUT[idx] = acc;
}

// ---- layer1 fused: H1[n] = relu(dn^2*G[x[n]] + sum w*G[x[s]] + b1), bf16 -
// one wave per node; lane holds cols {2l, 2l+1}; no atomics.
__global__ __launch_bounds__(256) void k_aggrelu(const int* __restrict__ x,
                                                 const float* __restrict__ G,
                                                 const float* __restrict__ b1,
                                                 const int* __restrict__ off,
                                                 const int* __restrict__ indeg,
                                                 const float* __restrict__ dis,
                                                 const int* __restrict__ csr_src,
                                                 const float* __restrict__ csr_norm,
                                                 unsigned short* __restrict__ H1,
                                                 int nn) {
  int n = (blockIdx.x * blockDim.x + threadIdx.x) >> 6;
  if (n >= nn) return;
  int lane = threadIdx.x & 63;
  float dn = dis[n];
  float2 g0 = ((const float2*)(G + (size_t)x[n] * D))[lane];
  float sn = dn * dn;
  float ax = sn * g0.x, ay = sn * g0.y;
  int s0 = off[n], m = indeg[n];
  for (int j = 0; j < m; ++j) {
    int s = csr_src[s0 + j];
    float w = csr_norm[s0 + j];
    float2 gv = ((const float2*)(G + (size_t)x[s] * D))[lane];
    ax += w * gv.x;
    ay += w * gv.y;
  }
  float2 bb = ((const float2*)b1)[lane];
  ushort2 o;
  o.x = f2bf(fmaxf(ax + bb.x, 0.f));
  o.y = f2bf(fmaxf(ay + bb.y, 0.f));
  ((ushort2*)(H1 + (size_t)n * D))[lane] = o;
}

// ---- layer2: AGG2[n] = dn^2*H1[n] + sum w*H1[s]  (f32 out, no atomics) ---
__global__ __launch_bounds__(256) void k_agg2(const unsigned short* __restrict__ H1,
                                              const int* __restrict__ off,
                                              const int* __restrict__ indeg,
                                              const float* __restrict__ dis,
                                              const int* __restrict__ csr_src,
                                              const float* __restrict__ csr_norm,
                                              float* __restrict__ AGG2, int nn) {
  int n = (blockIdx.x * blockDim.x + threadIdx.x) >> 6;
  if (n >= nn) return;
  int lane = threadIdx.x & 63;
  float dn = dis[n];
  ushort2 u = ((const ushort2*)(H1 + (size_t)n * D))[lane];
  float sn = dn * dn;
  float ax = sn * bf2f(u.x), ay = sn * bf2f(u.y);
  int s0 = off[n], m = indeg[n];
  for (int j = 0; j < m; ++j) {
    int s = csr_src[s0 + j];
    float w = csr_norm[s0 + j];
    ushort2 e = ((const ushort2*)(H1 + (size_t)s * D))[lane];
    ax += w * bf2f(e.x);
    ay += w * bf2f(e.y);
  }
  ((float2*)(AGG2 + (size_t)n * D))[lane] = make_float2(ax, ay);
}

// ---- pool: P[g][c] = sum over contiguous node range (batch sorted) -------
__global__ __launch_bounds__(128) void k_pool(const float* __restrict__ AGG2,
                                              const int* __restrict__ batch,
                                              float* __restrict__ P, int nn) {
  int g = blockIdx.x;
  int c = threadIdx.x;
  int lo = 0, hi = nn;
  while (lo < hi) { int m = (lo + hi) >> 1; if (batch[m] < g) lo = m + 1; else hi = m; }
  int s = lo;
  hi = nn;
  while (lo < hi) { int m = (lo + hi) >> 1; if (batch[m] < g + 1) lo = m + 1; else hi = m; }
  int e = lo;
  float sum = 0.f;
  for (int n = s; n < e; ++n) sum += AGG2[(size_t)n * D + c];
  P[(size_t)g * D + c] = sum;
}

// ---------------- out[g][c] = (P[g]/cnt[g]) @ W2 + b2, f32 out ------------
__global__ void k_out_dumb(const float* __restrict__ P,
                           const int* __restrict__ cnt,
                           const float* __restrict__ W2,
                           const float* __restrict__ b2,
                           float* __restrict__ Out, int ng) {
  int idx = blockIdx.x * blockDim.x + threadIdx.x;
  if (idx >= ng * D) return;
  int g = idx >> 7, c = idx & 127;
  int m = cnt[g];
  float inv = (m > 0) ? (1.0f / (float)m) : 0.0f;
  const float* pr = P + (size_t)g * D;
  float acc = 0.f;
  for (int k = 0; k < D; ++k) acc += pr[k] * W2[k * D + c];
  acc *= inv;
  if (m > 0) acc += b2[c];
  Out[idx] = acc;
}

extern "C" void kernel_launch(void* const* d_in, const int* in_sizes, int n_in,
                              void* d_out, int out_size, void* d_ws, size_t ws_size,
                              hipStream_t stream) {
  const void* xr = d_in[0];
  const void* eir = d_in[1];
  const void* batchr = d_in[2];
  const void* emb = d_in[3];
  const void* W1 = d_in[4];
  const void* b1 = d_in[5];
  const void* W2 = d_in[6];
  const void* b2 = d_in[7];
  float* out = (float*)d_out;

  const int nn = in_sizes[0];
  const int ne = in_sizes[1] / 2;
  const int vocab = in_sizes[3] / D;
  const int ng = out_size / D;
  const int nb = (nn + 1023) / 1024;

  char* p = (char*)d_ws;
  auto alloc = [&](size_t bytes) -> char* {
    char* r = p;
    p += (bytes + 511) & ~(size_t)511;
    return r;
  };
  int* flag = (int*)alloc(512);
  int* xs = (int*)alloc((size_t)nn * 4);
  int* srcs = (int*)alloc((size_t)ne * 4);
  int* dsts = (int*)alloc((size_t)ne * 4);
  int* batchs = (int*)alloc((size_t)nn * 4);
  int* indeg = (int*)alloc((size_t)nn * 4);
  int* off = (int*)alloc((size_t)nn * 4);
  int* cursor = (int*)alloc((size_t)nn * 4);
  float* dis = (float*)alloc((size_t)nn * 4);
  int* bsum = (int*)alloc((size_t)nb * 4);
  int* cnt = (int*)alloc((size_t)ng * 4);
  int* csr_src = (int*)alloc((size_t)ne * 4);
  float* csr_norm = (float*)alloc((size_t)ne * 4);
  float* embf = (float*)alloc((size_t)vocab * D * 4);
  float* W1f = (float*)alloc((size_t)D * D * 4);
  float* b1f = (float*)alloc((size_t)D * 4);
  float* W2f = (float*)alloc((size_t)D * D * 4);
  float* b2f = (float*)alloc((size_t)D * 4);
  float* G = (float*)alloc((size_t)vocab * D * 4);
  unsigned short* H1 = (unsigned short*)alloc((size_t)nn * D * 2);
  float* AGG2 = (float*)alloc((size_t)nn * D * 4);
  float* P = (float*)alloc((size_t)ng * D * 4);

  hipMemsetAsync(flag, 0, 512, stream);

  k_detect_f<<<1, 256, 0, stream>>>((const unsigned short*)emb, vocab * D, flag + 0);
  k_detect_f<<<1, 256, 0, stream>>>((const unsigned short*)W1, D * D, flag + 1);
  k_detect_f<<<1, 256, 0, stream>>>((const unsigned short*)b1, D, flag + 2);
  k_detect_f<<<1, 256, 0, stream>>>((const unsigned short*)W2, D * D, flag + 3);
  k_detect_f<<<1, 256, 0, stream>>>((const unsigned short*)b2, D, flag + 4);
  k_detect_i<<<1, 64, 0, stream>>>((const unsigned int*)eir, flag + 5);

  k_conv<<<(vocab * D + 255) / 256, 256, 0, stream>>>(emb, embf, vocab * D, flag + 0);
  k_conv<<<(D * D + 255) / 256, 256, 0, stream>>>(W1, W1f, D * D, flag + 1);
  k_conv<<<1, 128, 0, stream>>>(b1, b1f, D, flag + 2);
  k_conv<<<(D * D + 255) / 256, 256, 0, stream>>>(W2, W2f, D * D, flag + 3);
  k_conv<<<1, 128, 0, stream>>>(b2, b2f, D, flag + 4);

  k_convi<<<(nn + 255) / 256, 256, 0, stream>>>(xr, xs, 0, nn, 0x7fffffff, flag + 5);
  k_convi<<<(ne + 255) / 256, 256, 0, stream>>>(eir, srcs, 0, ne, nn, flag + 5);
  k_convi<<<(ne + 255) / 256, 256, 0, stream>>>(eir, dsts, ne, ne, nn, flag + 5);
  k_convi<<<(nn + 255) / 256, 256, 0, stream>>>(batchr, batchs, 0, nn, 0x7fffffff, flag + 5);

  k_max<<<(nn + 255) / 256, 256, 0, stream>>>(xs, nn, flag + 6);
  k_max<<<(nn + 255) / 256, 256, 0, stream>>>(batchs, nn, flag + 7);
  k_sdecide<<<1, 64, 0, stream>>>(flag);
  k_fixswap<<<(nn + 255) / 256, 256, 0, stream>>>(xs, batchs, nn, vocab, ng, flag);

  hipMemsetAsync(indeg, 0, (size_t)nn * 4, stream);
  hipMemsetAsync(cnt, 0, (size_t)ng * 4, stream);

  // CSR build
  k_count<<<(ne + 255) / 256, 256, 0, stream>>>(dsts, indeg, ne);
  k_bsum<<<nb, 256, 0, stream>>>(indeg, bsum, nn);
  k_scan2<<<1, 64, 0, stream>>>(bsum, nb);
  k_off<<<nb, 64, 0, stream>>>(indeg, bsum, off, cursor, nn);
  k_dis<<<(nn + 255) / 256, 256, 0, stream>>>(indeg, dis, nn);
  k_fill<<<(ne + 255) / 256, 256, 0, stream>>>(srcs, dsts, dis, cursor,
                                               csr_src, csr_norm, ne);
  k_cnt<<<(nn + 255) / 256, 256, 0, stream>>>(batchs, cnt, nn);

  // G = emb @ W1 (hoisted through embedding gather)
  k_gemm_dumb<<<(vocab * D + 255) / 256, 256, 0, stream>>>(embf, W1f, G, vocab);

  // layer 1 (gather, fused bias+relu) -> H1 bf16
  k_aggrelu<<<(nn * 64 + 255) / 256, 256, 0, stream>>>(xs, G, b1f, off, indeg, dis,
                                                       csr_src, csr_norm, H1, nn);
  // layer 2 (gather) -> AGG2 f32
  k_agg2<<<(nn * 64 + 255) / 256, 256, 0, stream>>>(H1, off, indeg, dis,
                                                    csr_src, csr_norm, AGG2, nn);
  // pool (batch sorted) + output GEMM
  k_pool<<<ng, 128, 0, stream>>>(AGG2, batchs, P, nn);
  k_out_dumb<<<(ng * D + 255) / 256, 256, 0, stream>>>(P, cnt, W2f, b2f, out, ng);
}

// Round 16
// 419.787 us; speedup vs baseline: 3.5966x; 1.4325x over previous
//
#include <hip/hip_runtime.h>
#include <hip/hip_bf16.h>

#define D 128

__device__ __forceinline__ float bf2f(unsigned short u) {
  return __uint_as_float(((unsigned int)u) << 16);
}
__device__ __forceinline__ unsigned short f2bf(float f) {
  unsigned int x = __float_as_uint(f);
  x += 0x7fff + ((x >> 16) & 1);
  return (unsigned short)(x >> 16);
}

// flags: [0..4]=float tensor is-bf16 (emb,W1,b1,W2,b2), [5]=ints-int64,
//        [6]=max(x), [7]=max(batch), [8]=x/batch swapped

// fused float-dtype detect: block b probes tensor b
__global__ void k_detect_f5(const unsigned short* __restrict__ t0, int n0,
                            const unsigned short* __restrict__ t1, int n1,
                            const unsigned short* __restrict__ t2, int n2,
                            const unsigned short* __restrict__ t3, int n3,
                            const unsigned short* __restrict__ t4, int n4,
                            int* __restrict__ flag) {
  const unsigned short* tabs[5] = {t0, t1, t2, t3, t4};
  int ns[5] = {n0, n1, n2, n3, n4};
  int b = blockIdx.x;
  const unsigned short* u16 = tabs[b];
  int n = ns[b];
  __shared__ int cnt;
  int K = n / 2 < 256 ? n / 2 : 256;
  if (threadIdx.x == 0) cnt = 0;
  __syncthreads();
  if (threadIdx.x < K) {
    unsigned short u = u16[threadIdx.x * 2];
    int e = (u >> 7) & 0xFF;
    if (u == 0 || (e >= 100 && e <= 140)) atomicAdd(&cnt, 1);
  }
  __syncthreads();
  if (threadIdx.x == 0) flag[b] = (cnt * 2 >= K) ? 1 : 0;
}

__global__ void k_detect_i(const unsigned int* __restrict__ ei32,
                           int* __restrict__ flagSlot) {
  __shared__ int z;
  if (threadIdx.x == 0) z = 0;
  __syncthreads();
  if (ei32[threadIdx.x * 2 + 1] == 0u) atomicAdd(&z, 1);
  __syncthreads();
  if (threadIdx.x == 0) *flagSlot = (z >= 60) ? 1 : 0;
}

__global__ void k_conv(const void* __restrict__ src, float* __restrict__ dst,
                       int n, const int* __restrict__ flagSlot) {
  int i = blockIdx.x * blockDim.x + threadIdx.x;
  if (i >= n) return;
  if (*flagSlot) dst[i] = bf2f(((const unsigned short*)src)[i]);
  else           dst[i] = ((const float*)src)[i];
}

// fused param conversion: W1 | b1 | W2 | b2 (each with own dtype flag)
__global__ void k_conv_params(const void* __restrict__ W1, const void* __restrict__ b1,
                              const void* __restrict__ W2, const void* __restrict__ b2,
                              float* __restrict__ W1f, float* __restrict__ b1f,
                              float* __restrict__ W2f, float* __restrict__ b2f,
                              const int* __restrict__ flag) {
  int i = blockIdx.x * blockDim.x + threadIdx.x;
  const int S = D * D;
  const void* src; float* dst; int j; const int* fs;
  if (i < S)                { src = W1; dst = W1f; j = i;            fs = flag + 1; }
  else if (i < S + D)       { src = b1; dst = b1f; j = i - S;        fs = flag + 2; }
  else if (i < 2 * S + D)   { src = W2; dst = W2f; j = i - S - D;    fs = flag + 3; }
  else if (i < 2 * S + 2*D) { src = b2; dst = b2f; j = i - 2*S - D;  fs = flag + 4; }
  else return;
  if (*fs) dst[j] = bf2f(((const unsigned short*)src)[j]);
  else     dst[j] = ((const float*)src)[j];
}

// fused int conversion: xs | srcs | dsts | batchs
__global__ void k_convi_all(const void* __restrict__ xr, const void* __restrict__ eir,
                            const void* __restrict__ br,
                            int* __restrict__ xs, int* __restrict__ srcs,
                            int* __restrict__ dsts, int* __restrict__ batchs,
                            int nn, int ne, const int* __restrict__ flag64) {
  long long i = (long long)blockIdx.x * blockDim.x + threadIdx.x;
  int is64 = *flag64;
  if (i < nn) {
    int v = is64 ? (int)((const long long*)xr)[i] : ((const int*)xr)[i];
    xs[i] = v < 0 ? 0 : v;
  } else if (i < (long long)nn + ne) {
    long long j = i - nn;
    int v = is64 ? (int)((const long long*)eir)[j] : ((const int*)eir)[j];
    v = v < 0 ? 0 : (v > nn - 1 ? nn - 1 : v);
    srcs[j] = v;
  } else if (i < (long long)nn + 2 * ne) {
    long long j = i - nn - ne;
    int v = is64 ? (int)((const long long*)eir)[ne + j] : ((const int*)eir)[ne + j];
    v = v < 0 ? 0 : (v > nn - 1 ? nn - 1 : v);
    dsts[j] = v;
  } else if (i < 2LL * nn + 2 * ne) {
    long long j = i - nn - 2 * ne;
    int v = is64 ? (int)((const long long*)br)[j] : ((const int*)br)[j];
    batchs[j] = v < 0 ? 0 : v;
  }
}

// fused max(x), max(batch): LDS reduce, one atomic per block per target
__global__ __launch_bounds__(256) void k_max2(const int* __restrict__ xs,
                                              const int* __restrict__ bs,
                                              int nn, int* __restrict__ flag) {
  __shared__ int mx[256], mb[256];
  int t = threadIdx.x;
  int i = blockIdx.x * 256 + t;
  mx[t] = (i < nn) ? xs[i] : 0;
  mb[t] = (i < nn) ? bs[i] : 0;
  __syncthreads();
  for (int w = 128; w > 0; w >>= 1) {
    if (t < w) {
      mx[t] = mx[t] > mx[t + w] ? mx[t] : mx[t + w];
      mb[t] = mb[t] > mb[t + w] ? mb[t] : mb[t + w];
    }
    __syncthreads();
  }
  if (t == 0) { atomicMax(&flag[6], mx[0]); atomicMax(&flag[7], mb[0]); }
}

__global__ void k_sdecide(int* __restrict__ flag) {
  if (threadIdx.x == 0 && blockIdx.x == 0) flag[8] = (flag[6] < flag[7]) ? 1 : 0;
}

__global__ void k_fixswap(int* __restrict__ xs, int* __restrict__ bs, int nn,
                          int vocab, int ng, const int* __restrict__ flag) {
  int i = blockIdx.x * blockDim.x + threadIdx.x;
  if (i >= nn) return;
  int a = xs[i], b = bs[i];
  if (flag[8]) { int t = a; a = b; b = t; }
  a = a < 0 ? 0 : (a > vocab - 1 ? vocab - 1 : a);
  b = b < 0 ? 0 : (b > ng - 1 ? ng - 1 : b);
  xs[i] = a;
  bs[i] = b;
}

// ---------------- CSR build ------------------------------------------------
__global__ void k_count(const int* __restrict__ dstA, int* __restrict__ indeg,
                        int ne) {
  int e = blockIdx.x * blockDim.x + threadIdx.x;
  if (e < ne) atomicAdd(&indeg[dstA[e]], 1);
}

// hierarchical scan (r2-proven): per-1024 block exclusive scan + block sums
__global__ __launch_bounds__(1024) void k_scan1(const int* __restrict__ indeg,
                                                int* __restrict__ off,
                                                int* __restrict__ bsum, int nn) {
  int t = threadIdx.x;
  int idx = blockIdx.x * 1024 + t;
  int v = (idx < nn) ? indeg[idx] : 0;
  int lane = t & 63, wid = t >> 6;
  int inc = v;
  #pragma unroll
  for (int d = 1; d < 64; d <<= 1) {
    int u = __shfl_up(inc, d);
    if (lane >= d) inc += u;
  }
  __shared__ int ws[16];
  if (lane == 63) ws[wid] = inc;
  __syncthreads();
  if (wid == 0) {
    int wv = (lane < 16) ? ws[lane] : 0;
    #pragma unroll
    for (int d = 1; d < 16; d <<= 1) {
      int u = __shfl_up(wv, d);
      if (lane >= d) wv += u;
    }
    if (lane < 16) ws[lane] = wv;
  }
  __syncthreads();
  int base = wid ? ws[wid - 1] : 0;
  if (idx < nn) off[idx] = base + inc - v;
  if (t == 1023) bsum[blockIdx.x] = ws[15];
}

__global__ void k_scan2(int* __restrict__ bsum, int nb) {
  if (blockIdx.x == 0 && threadIdx.x == 0) {
    int run = 0;
    for (int i = 0; i < nb; ++i) { int s = bsum[i]; bsum[i] = run; run += s; }
  }
}

__global__ void k_scan3(int* __restrict__ off, int* __restrict__ cursor,
                        float* __restrict__ dis, const int* __restrict__ indeg,
                        const int* __restrict__ bsum, int nn) {
  int idx = blockIdx.x * blockDim.x + threadIdx.x;
  if (idx >= nn) return;
  int o = off[idx] + bsum[idx >> 10];
  off[idx] = o;
  cursor[idx] = o;
  dis[idx] = rsqrtf((float)indeg[idx] + 1.0f);  // +1 self-loop
}

__global__ void k_fill(const int* __restrict__ srcA, const int* __restrict__ dstA,
                       const float* __restrict__ dis, int* __restrict__ cursor,
                       int* __restrict__ csr_src, float* __restrict__ csr_norm,
                       int ne) {
  int e = blockIdx.x * blockDim.x + threadIdx.x;
  if (e >= ne) return;
  int d = dstA[e], s = srcA[e];
  int pp = atomicAdd(&cursor[d], 1);
  csr_src[pp] = s;
  csr_norm[pp] = dis[s] * dis[d];
}

// ---------------- G = emb @ W1 --------------------------------------------
__global__ void k_gemm_dumb(const float* __restrict__ A,
                            const float* __restrict__ W,
                            float* __restrict__ OUT, int rows) {
  int idx = blockIdx.x * blockDim.x + threadIdx.x;
  if (idx >= rows * D) return;
  int r = idx >> 7, c = idx & 127;
  const float* a = A + (size_t)r * D;
  float acc = 0.f;
  for (int k = 0; k < D; ++k) acc += a[k] * W[k * D + c];
  OUT[idx] = acc;
}

// ---- layer1 fused: H1[n] = relu(dn^2*G[x[n]] + sum w*G[x[s]] + b1), bf16 -
__global__ __launch_bounds__(256) void k_aggrelu(const int* __restrict__ x,
                                                 const float* __restrict__ G,
                                                 const float* __restrict__ b1,
                                                 const int* __restrict__ off,
                                                 const int* __restrict__ indeg,
                                                 const float* __restrict__ dis,
                                                 const int* __restrict__ csr_src,
                                                 const float* __restrict__ csr_norm,
                                                 unsigned short* __restrict__ H1,
                                                 int nn) {
  int n = (blockIdx.x * blockDim.x + threadIdx.x) >> 6;
  if (n >= nn) return;
  int lane = threadIdx.x & 63;
  float dn = dis[n];
  float2 g0 = ((const float2*)(G + (size_t)x[n] * D))[lane];
  float sn = dn * dn;
  float ax = sn * g0.x, ay = sn * g0.y;
  int s0 = off[n], m = indeg[n];
  for (int j = 0; j < m; ++j) {
    int s = csr_src[s0 + j];
    float w = csr_norm[s0 + j];
    float2 gv = ((const float2*)(G + (size_t)x[s] * D))[lane];
    ax += w * gv.x;
    ay += w * gv.y;
  }
  float2 bb = ((const float2*)b1)[lane];
  ushort2 o;
  o.x = f2bf(fmaxf(ax + bb.x, 0.f));
  o.y = f2bf(fmaxf(ay + bb.y, 0.f));
  ((ushort2*)(H1 + (size_t)n * D))[lane] = o;
}

// ---- layer2: AGG2[n] = dn^2*H1[n] + sum w*H1[s]  (f32 out, no atomics) ---
__global__ __launch_bounds__(256) void k_agg2(const unsigned short* __restrict__ H1,
                                              const int* __restrict__ off,
                                              const int* __restrict__ indeg,
                                              const float* __restrict__ dis,
                                              const int* __restrict__ csr_src,
                                              const float* __restrict__ csr_norm,
                                              float* __restrict__ AGG2, int nn) {
  int n = (blockIdx.x * blockDim.x + threadIdx.x) >> 6;
  if (n >= nn) return;
  int lane = threadIdx.x & 63;
  float dn = dis[n];
  ushort2 u = ((const ushort2*)(H1 + (size_t)n * D))[lane];
  float sn = dn * dn;
  float ax = sn * bf2f(u.x), ay = sn * bf2f(u.y);
  int s0 = off[n], m = indeg[n];
  for (int j = 0; j < m; ++j) {
    int s = csr_src[s0 + j];
    float w = csr_norm[s0 + j];
    ushort2 e = ((const ushort2*)(H1 + (size_t)s * D))[lane];
    ax += w * bf2f(e.x);
    ay += w * bf2f(e.y);
  }
  ((float2*)(AGG2 + (size_t)n * D))[lane] = make_float2(ax, ay);
}

// ---- pool: P[g][c] = sum over node range (batch sorted); also cnt[g] -----
__global__ __launch_bounds__(128) void k_pool(const float* __restrict__ AGG2,
                                              const int* __restrict__ batch,
                                              float* __restrict__ P,
                                              int* __restrict__ cnt, int nn) {
  int g = blockIdx.x;
  int c = threadIdx.x;
  int lo = 0, hi = nn;
  while (lo < hi) { int m = (lo + hi) >> 1; if (batch[m] < g) lo = m + 1; else hi = m; }
  int s = lo;
  hi = nn;
  while (lo < hi) { int m = (lo + hi) >> 1; if (batch[m] < g + 1) lo = m + 1; else hi = m; }
  int e = lo;
  float sum = 0.f;
  for (int n = s; n < e; ++n) sum += AGG2[(size_t)n * D + c];
  P[(size_t)g * D + c] = sum;
  if (c == 0) cnt[g] = e - s;
}

// ---------------- out[g][c] = (P[g]/cnt[g]) @ W2 + b2, f32 out ------------
__global__ void k_out_dumb(const float* __restrict__ P,
                           const int* __restrict__ cnt,
                           const float* __restrict__ W2,
                           const float* __restrict__ b2,
                           float* __restrict__ Out, int ng) {
  int idx = blockIdx.x * blockDim.x + threadIdx.x;
  if (idx >= ng * D) return;
  int g = idx >> 7, c = idx & 127;
  int m = cnt[g];
  float inv = (m > 0) ? (1.0f / (float)m) : 0.0f;
  const float* pr = P + (size_t)g * D;
  float acc = 0.f;
  for (int k = 0; k < D; ++k) acc += pr[k] * W2[k * D + c];
  acc *= inv;
  if (m > 0) acc += b2[c];
  Out[idx] = acc;
}

extern "C" void kernel_launch(void* const* d_in, const int* in_sizes, int n_in,
                              void* d_out, int out_size, void* d_ws, size_t ws_size,
                              hipStream_t stream) {
  const void* xr = d_in[0];
  const void* eir = d_in[1];
  const void* batchr = d_in[2];
  const void* emb = d_in[3];
  const void* W1 = d_in[4];
  const void* b1 = d_in[5];
  const void* W2 = d_in[6];
  const void* b2 = d_in[7];
  float* out = (float*)d_out;

  const int nn = in_sizes[0];
  const int ne = in_sizes[1] / 2;
  const int vocab = in_sizes[3] / D;
  const int ng = out_size / D;
  const int nb = (nn + 1023) / 1024;

  char* p = (char*)d_ws;
  auto alloc = [&](size_t bytes) -> char* {
    char* r = p;
    p += (bytes + 511) & ~(size_t)511;
    return r;
  };
  int* flag = (int*)alloc(512);
  int* xs = (int*)alloc((size_t)nn * 4);
  int* srcs = (int*)alloc((size_t)ne * 4);
  int* dsts = (int*)alloc((size_t)ne * 4);
  int* batchs = (int*)alloc((size_t)nn * 4);
  int* indeg = (int*)alloc((size_t)nn * 4);
  int* off = (int*)alloc((size_t)nn * 4);
  int* cursor = (int*)alloc((size_t)nn * 4);
  float* dis = (float*)alloc((size_t)nn * 4);
  int* bsum = (int*)alloc((size_t)nb * 4);
  int* cnt = (int*)alloc((size_t)ng * 4);
  int* csr_src = (int*)alloc((size_t)ne * 4);
  float* csr_norm = (float*)alloc((size_t)ne * 4);
  float* embf = (float*)alloc((size_t)vocab * D * 4);
  float* W1f = (float*)alloc((size_t)D * D * 4);
  float* b1f = (float*)alloc((size_t)D * 4);
  float* W2f = (float*)alloc((size_t)D * D * 4);
  float* b2f = (float*)alloc((size_t)D * 4);
  float* G = (float*)alloc((size_t)vocab * D * 4);
  unsigned short* H1 = (unsigned short*)alloc((size_t)nn * D * 2);
  float* AGG2 = (float*)alloc((size_t)nn * D * 4);
  float* P = (float*)alloc((size_t)ng * D * 4);

  hipMemsetAsync(flag, 0, 512, stream);

  k_detect_f5<<<5, 256, 0, stream>>>(
      (const unsigned short*)emb, vocab * D,
      (const unsigned short*)W1, D * D,
      (const unsigned short*)b1, D,
      (const unsigned short*)W2, D * D,
      (const unsigned short*)b2, D, flag);
  k_detect_i<<<1, 64, 0, stream>>>((const unsigned int*)eir, flag + 5);

  k_conv<<<(vocab * D + 255) / 256, 256, 0, stream>>>(emb, embf, vocab * D, flag + 0);
  k_conv_params<<<(2 * D * D + 2 * D + 255) / 256, 256, 0, stream>>>(
      W1, b1, W2, b2, W1f, b1f, W2f, b2f, flag);

  {
    long long tot = 2LL * nn + 2LL * ne;
    k_convi_all<<<(int)((tot + 255) / 256), 256, 0, stream>>>(
        xr, eir, batchr, xs, srcs, dsts, batchs, nn, ne, flag + 5);
  }
  k_max2<<<(nn + 255) / 256, 256, 0, stream>>>(xs, batchs, nn, flag);
  k_sdecide<<<1, 64, 0, stream>>>(flag);
  k_fixswap<<<(nn + 255) / 256, 256, 0, stream>>>(xs, batchs, nn, vocab, ng, flag);

  hipMemsetAsync(indeg, 0, (size_t)nn * 4, stream);

  // CSR build (hierarchical scan; no serial bottleneck)
  k_count<<<(ne + 255) / 256, 256, 0, stream>>>(dsts, indeg, ne);
  k_scan1<<<nb, 1024, 0, stream>>>(indeg, off, bsum, nn);
  k_scan2<<<1, 64, 0, stream>>>(bsum, nb);
  k_scan3<<<(nn + 255) / 256, 256, 0, stream>>>(off, cursor, dis, indeg, bsum, nn);
  k_fill<<<(ne + 255) / 256, 256, 0, stream>>>(srcs, dsts, dis, cursor,
                                               csr_src, csr_norm, ne);

  // G = emb @ W1 (hoisted through embedding gather)
  k_gemm_dumb<<<(vocab * D + 255) / 256, 256, 0, stream>>>(embf, W1f, G, vocab);

  // layer 1 (gather, fused bias+relu) -> H1 bf16
  k_aggrelu<<<(nn * 64 + 255) / 256, 256, 0, stream>>>(xs, G, b1f, off, indeg, dis,
                                                       csr_src, csr_norm, H1, nn);
  // layer 2 (gather) -> AGG2 f32
  k_agg2<<<(nn * 64 + 255) / 256, 256, 0, stream>>>(H1, off, indeg, dis,
                                                    csr_src, csr_norm, AGG2, nn);
  // pool (batch sorted; also emits cnt) + output GEMM
  k_pool<<<ng, 128, 0, stream>>>(AGG2, batchs, P, cnt, nn);
  k_out_dumb<<<(ng * D + 255) / 256, 256, 0, stream>>>(P, cnt, W2f, b2f, out, ng);
}